// Round 15
// baseline (4117.523 us; speedup 1.0000x reference)
//
#include <hip/hip_runtime.h>
#include <hip/hip_fp16.h>

#define B 32
#define S 512
#define E 512
#define H 512
#define NH 8
#define HD 64

typedef _Float16 h16x8 __attribute__((ext_vector_type(8)));
typedef _Float16 h16x4 __attribute__((ext_vector_type(4)));
typedef _Float16 h16x2 __attribute__((ext_vector_type(2)));
typedef float f32x4 __attribute__((ext_vector_type(4)));

#if __has_builtin(__builtin_amdgcn_fdot2)
__device__ __forceinline__ float dot2f(h16x2 a, h16x2 b, float c) {
    return __builtin_amdgcn_fdot2(a, b, c, false);
}
#else
__device__ __forceinline__ float dot2f(h16x2 a, h16x2 b, float c) {
    return c + (float)a[0] * (float)b[0] + (float)a[1] * (float)b[1];
}
#endif

__device__ __forceinline__ h16x2 pr(h16x8 v, int q) {
    h16x2 r; r[0] = v[2 * q]; r[1] = v[2 * q + 1]; return r;
}

// ---------------- fp32 -> fp16 cast (vectorized, grid-stride) ----------------
__global__ __launch_bounds__(256) void cast_h(const float* __restrict__ src,
                                              _Float16* __restrict__ dst, int n4) {
    int i = blockIdx.x * 256 + threadIdx.x;
    const int stride = gridDim.x * 256;
    for (; i < n4; i += stride) {
        float4 v = ((const float4*)src)[i];
        h16x4 o;
        o[0] = (_Float16)v.x; o[1] = (_Float16)v.y;
        o[2] = (_Float16)v.z; o[3] = (_Float16)v.w;
        ((h16x4*)dst)[i] = o;
    }
}

// ---------------- pack Whh into the rnn_batch consumption order ----------------
// Thread thr=(jg<<2)|kq of rnn_batch needs chunk n=(c8<<2)|r =
// W[jg*4+r][kq*128+c8*8 .. +8]  ->  Wp[(n*512+thr)*8]  (coalesced at fixed n).
__global__ __launch_bounds__(256) void pack_w(const float* __restrict__ W,
                                              _Float16* __restrict__ Wp) {
    const int o = blockIdx.x * 256 + threadIdx.x;   // 0 .. 32767
    const int n = o >> 9, thr = o & 511;
    const int c8 = n >> 2, r = n & 3;
    const int jg = thr >> 2, kq = thr & 3;
    const float* s = &W[(size_t)(jg * 4 + r) * 512 + kq * 128 + c8 * 8];
    float4 u0 = *(const float4*)s;
    float4 u1 = *(const float4*)(s + 4);
    h16x8 v;
    v[0] = (_Float16)u0.x; v[1] = (_Float16)u0.y; v[2] = (_Float16)u0.z; v[3] = (_Float16)u0.w;
    v[4] = (_Float16)u1.x; v[5] = (_Float16)u1.y; v[6] = (_Float16)u1.z; v[7] = (_Float16)u1.w;
    *(h16x8*)&Wp[(size_t)o * 8] = v;
}

// ---------------- MFMA GEMM: C[M,N] = A[M,K] @ W[N,K]^T + bias ----------------
// OMODE 0: f32 row-major. 1: f16 row-major. 2: f16 scattered to Vt[(b*8+h)*64+d][s].
// 3: f32 time-major scatter row r=b*512+s -> C[(s*32+b)*N+c].
template <int OMODE>
__global__ __launch_bounds__(256) void gemm_mfma(const _Float16* __restrict__ A,
                                                 const _Float16* __restrict__ W,
                                                 const float* __restrict__ bias,
                                                 void* __restrict__ Cout,
                                                 int M, int N, int K) {
    __shared__ __align__(16) _Float16 Als[128 * 32];
    __shared__ __align__(16) _Float16 Bls[128 * 32];
    const int tid = threadIdx.x;
    const int m0 = blockIdx.y * 128;
    const int n0 = blockIdx.x * 128;
    const int lane = tid & 63;
    const int w = tid >> 6;
    const int wm = w >> 1, wn = w & 1;
    f32x4 acc[4][4] = {};

    const int srow = tid >> 1;
    const int shalf = tid & 1;
    const _Float16* Ag = A + (size_t)(m0 + srow) * K + shalf * 16;
    const _Float16* Wg = W + (size_t)(n0 + srow) * K + shalf * 16;

    for (int k0 = 0; k0 < K; k0 += 32) {
        h16x8 a0 = *(const h16x8*)(Ag + k0);
        h16x8 a1 = *(const h16x8*)(Ag + k0 + 8);
        h16x8 b0 = *(const h16x8*)(Wg + k0);
        h16x8 b1 = *(const h16x8*)(Wg + k0 + 8);
        __syncthreads();
        *(h16x8*)&Als[srow * 32 + shalf * 16] = a0;
        *(h16x8*)&Als[srow * 32 + shalf * 16 + 8] = a1;
        *(h16x8*)&Bls[srow * 32 + shalf * 16] = b0;
        *(h16x8*)&Bls[srow * 32 + shalf * 16 + 8] = b1;
        __syncthreads();
        h16x8 af[4], bf[4];
#pragma unroll
        for (int mt = 0; mt < 4; ++mt)
            af[mt] = *(const h16x8*)&Als[(wm * 64 + mt * 16 + (lane & 15)) * 32 + (lane >> 4) * 8];
#pragma unroll
        for (int nt = 0; nt < 4; ++nt)
            bf[nt] = *(const h16x8*)&Bls[(wn * 64 + nt * 16 + (lane & 15)) * 32 + (lane >> 4) * 8];
#pragma unroll
        for (int mt = 0; mt < 4; ++mt)
#pragma unroll
            for (int nt = 0; nt < 4; ++nt)
                acc[mt][nt] = __builtin_amdgcn_mfma_f32_16x16x32_f16(af[mt], bf[nt], acc[mt][nt], 0, 0, 0);
    }

    float* Cf = (float*)Cout;
    _Float16* Ch = (_Float16*)Cout;
    const int colb = n0 + wn * 64 + (lane & 15);
    const int rowb = m0 + wm * 64 + ((lane >> 4) << 2);
#pragma unroll
    for (int mt = 0; mt < 4; ++mt) {
#pragma unroll
        for (int nt = 0; nt < 4; ++nt) {
            const int c = colb + nt * 16;
            const float bv = bias[c];
            if (OMODE == 2) {
                const int R0 = rowb + mt * 16;
                const int bb = R0 >> 9, s = R0 & 511, hh = c >> 6, d = c & 63;
                h16x4 pk;
#pragma unroll
                for (int j = 0; j < 4; ++j) pk[j] = (_Float16)(acc[mt][nt][j] + bv);
                *(h16x4*)&Ch[((size_t)(bb * 8 + hh) * 64 + d) * 512 + s] = pk;
            } else {
#pragma unroll
                for (int j = 0; j < 4; ++j) {
                    const int R = rowb + mt * 16 + j;
                    const float v = acc[mt][nt][j] + bv;
                    if (OMODE == 0) Cf[(size_t)R * N + c] = v;
                    else if (OMODE == 3) Cf[((size_t)(R & 511) * 32 + (R >> 9)) * N + c] = v;
                    else Ch[(size_t)R * N + c] = (_Float16)v;
                }
            }
        }
    }
}

// ---------------- MFMA flash attention: per (b, h, 64-row q-tile) ----------------
__global__ __launch_bounds__(256) void attn_mfma(_Float16* __restrict__ Qb,
                                                 const _Float16* __restrict__ Kb,
                                                 const _Float16* __restrict__ Vt) {
    __shared__ __align__(16) _Float16 Qs[64 * 72];
    __shared__ __align__(16) _Float16 Ks[64 * 72];
    __shared__ __align__(16) _Float16 Vs[64 * 72];
    __shared__ __align__(16) _Float16 Ps[4 * 16 * 72];
    const int tid = threadIdx.x;
    const int lane = tid & 63;
    const int w = tid >> 6;
    const int qt = blockIdx.x & 7;
    const int h = (blockIdx.x >> 3) & 7;
    const int b = blockIdx.x >> 6;
    const size_t qrow0 = (size_t)b * 512 + qt * 64;
    const int col0 = h * 64;

    {
        const int r = tid >> 2;
        const int c0 = (tid & 3) << 4;
        const _Float16* gq = &Qb[(qrow0 + r) * 512 + col0 + c0];
        *(h16x8*)&Qs[r * 72 + c0] = *(const h16x8*)(gq);
        *(h16x8*)&Qs[r * 72 + c0 + 8] = *(const h16x8*)(gq + 8);
    }
    __syncthreads();
    h16x8 aq[2];
#pragma unroll
    for (int ks = 0; ks < 2; ++ks)
        aq[ks] = *(const h16x8*)&Qs[(w * 16 + (lane & 15)) * 72 + ks * 32 + (lane >> 4) * 8];

    float m[4] = {-1e30f, -1e30f, -1e30f, -1e30f};
    float l[4] = {0.f, 0.f, 0.f, 0.f};
    f32x4 acco[4] = {};

    for (int kt = 0; kt < 8; ++kt) {
        __syncthreads();
        {
            const int r = tid >> 2;
            const int c0 = (tid & 3) << 4;
            const _Float16* gk = &Kb[((size_t)b * 512 + kt * 64 + r) * 512 + col0 + c0];
            *(h16x8*)&Ks[r * 72 + c0] = *(const h16x8*)(gk);
            *(h16x8*)&Ks[r * 72 + c0 + 8] = *(const h16x8*)(gk + 8);
            const _Float16* gv = &Vt[((size_t)(b * 8 + h) * 64 + r) * 512 + kt * 64 + c0];
            *(h16x8*)&Vs[r * 72 + c0] = *(const h16x8*)(gv);
            *(h16x8*)&Vs[r * 72 + c0 + 8] = *(const h16x8*)(gv + 8);
        }
        __syncthreads();
        f32x4 accs[4] = {};
#pragma unroll
        for (int nt = 0; nt < 4; ++nt) {
#pragma unroll
            for (int ks = 0; ks < 2; ++ks) {
                h16x8 bk = *(const h16x8*)&Ks[(nt * 16 + (lane & 15)) * 72 + ks * 32 + (lane >> 4) * 8];
                accs[nt] = __builtin_amdgcn_mfma_f32_16x16x32_f16(aq[ks], bk, accs[nt], 0, 0, 0);
            }
        }
#pragma unroll
        for (int j = 0; j < 4; ++j) {
            float v = fmaxf(fmaxf(accs[0][j], accs[1][j]), fmaxf(accs[2][j], accs[3][j]));
#pragma unroll
            for (int o = 1; o < 16; o <<= 1) v = fmaxf(v, __shfl_xor(v, o, 64));
            const float mn = fmaxf(m[j], v);
            const float scl = __expf(0.125f * (m[j] - mn));
            m[j] = mn;
            l[j] *= scl;
#pragma unroll
            for (int nt2 = 0; nt2 < 4; ++nt2) acco[nt2][j] *= scl;
            float ps = 0.f;
            const int prow = ((lane >> 4) << 2) + j;
#pragma unroll
            for (int nt = 0; nt < 4; ++nt) {
                const float p = __expf(0.125f * (accs[nt][j] - mn));
                ps += p;
                Ps[w * 16 * 72 + prow * 72 + nt * 16 + (lane & 15)] = (_Float16)p;
            }
#pragma unroll
            for (int o = 1; o < 16; o <<= 1) ps += __shfl_xor(ps, o, 64);
            l[j] += ps;
        }
        __syncthreads();
#pragma unroll
        for (int ks2 = 0; ks2 < 2; ++ks2) {
            h16x8 pa = *(const h16x8*)&Ps[w * 16 * 72 + (lane & 15) * 72 + ks2 * 32 + (lane >> 4) * 8];
#pragma unroll
            for (int nt2 = 0; nt2 < 4; ++nt2) {
                h16x8 bv = *(const h16x8*)&Vs[(nt2 * 16 + (lane & 15)) * 72 + ks2 * 32 + (lane >> 4) * 8];
                acco[nt2] = __builtin_amdgcn_mfma_f32_16x16x32_f16(pa, bv, acco[nt2], 0, 0, 0);
            }
        }
    }
#pragma unroll
    for (int j = 0; j < 4; ++j) {
        const float inv = 1.0f / l[j];
        const size_t r = qrow0 + w * 16 + ((lane >> 4) << 2) + j;
#pragma unroll
        for (int nt2 = 0; nt2 < 4; ++nt2)
            Qb[r * 512 + col0 + nt2 * 16 + (lane & 15)] = (_Float16)(acco[nt2][j] * inv);
    }
}

// ---------------- per-batch RNN layer: 32 blocks x 512 threads, no cross-block sync --
// Block b owns the whole chain for batch b. h ping-pongs in LDS (fp16, bank-quadrant
// layout). Weights stream from L2 in the packed coalesced order (Wp). Thread
// (jg=tid>>2, kq=tid&3) computes j = jg*4..+3 over k in [kq*128, +128); reduce over
// kq via 2 shfl_xor(width 4). One __syncthreads per step. h time-series stored to
// global fp16 (plain stores, off the critical path) for the next layer / fc.
__global__ __launch_bounds__(512, 2) void rnn_batch(const float* __restrict__ pre,
                                                    const _Float16* __restrict__ Wp,
                                                    const float* __restrict__ bhh,
                                                    _Float16* __restrict__ hout) {
    __shared__ __align__(16) _Float16 hl[2][4 * 136];   // 4 kq slices, 8-half pad each
    const int tid = threadIdx.x;
    const int b = blockIdx.x;
    const int jg = tid >> 2, kq = tid & 3;
    const int j0 = jg * 4;
    float4 bj = {0.f, 0.f, 0.f, 0.f};
    if (kq == 0) bj = *(const float4*)&bhh[j0];

    for (int t = 0; t < S; ++t) {
        float4 pv = {0.f, 0.f, 0.f, 0.f};
        if (kq == 0) pv = *(const float4*)&pre[((size_t)t * 32 + b) * 512 + j0];
        float a0 = 0.f, a1 = 0.f, a2 = 0.f, a3 = 0.f;
        if (t > 0) {
            const _Float16* hb = &hl[t & 1][kq * 136];
#pragma unroll
            for (int c8 = 0; c8 < 16; ++c8) {
                h16x8 hx = *(const h16x8*)&hb[c8 * 8];
                const _Float16* wb = &Wp[((size_t)(c8 * 4) * 512 + tid) * 8];
                h16x8 w0 = *(const h16x8*)(wb);
                h16x8 w1 = *(const h16x8*)(wb + 512 * 8);
                h16x8 w2 = *(const h16x8*)(wb + 1024 * 8);
                h16x8 w3 = *(const h16x8*)(wb + 1536 * 8);
#pragma unroll
                for (int q = 0; q < 4; ++q) {
                    const h16x2 hq = pr(hx, q);
                    a0 = dot2f(pr(w0, q), hq, a0);
                    a1 = dot2f(pr(w1, q), hq, a1);
                    a2 = dot2f(pr(w2, q), hq, a2);
                    a3 = dot2f(pr(w3, q), hq, a3);
                }
            }
        }
        a0 += __shfl_xor(a0, 1, 4); a0 += __shfl_xor(a0, 2, 4);
        a1 += __shfl_xor(a1, 1, 4); a1 += __shfl_xor(a1, 2, 4);
        a2 += __shfl_xor(a2, 1, 4); a2 += __shfl_xor(a2, 2, 4);
        a3 += __shfl_xor(a3, 1, 4); a3 += __shfl_xor(a3, 2, 4);
        if (kq == 0) {
            float s0 = a0 + pv.x + bj.x;
            float s1 = a1 + pv.y + bj.y;
            float s2 = a2 + pv.z + bj.z;
            float s3 = a3 + pv.w + bj.w;
            s0 = fminf(fmaxf(s0, -15.f), 15.f);
            s1 = fminf(fmaxf(s1, -15.f), 15.f);
            s2 = fminf(fmaxf(s2, -15.f), 15.f);
            s3 = fminf(fmaxf(s3, -15.f), 15.f);
            const float e0 = __expf(2.f * s0), e1 = __expf(2.f * s1);
            const float e2 = __expf(2.f * s2), e3 = __expf(2.f * s3);
            h16x4 pk;
            pk[0] = (_Float16)((e0 - 1.f) / (e0 + 1.f));
            pk[1] = (_Float16)((e1 - 1.f) / (e1 + 1.f));
            pk[2] = (_Float16)((e2 - 1.f) / (e2 + 1.f));
            pk[3] = (_Float16)((e3 - 1.f) / (e3 + 1.f));
            *(h16x4*)&hl[1 - (t & 1)][(j0 >> 7) * 136 + (j0 & 127)] = pk;
            *(h16x4*)&hout[((size_t)t * 32 + b) * 512 + j0] = pk;
        }
        __syncthreads();
    }
}

// ---------------- final FC: out[b] = h1[511][b,:] . Wfc[0,:] + bfc[0] ----------------
__global__ __launch_bounds__(64) void fc_out(const _Float16* __restrict__ hh,
                                             const float* __restrict__ Wfc,
                                             const float* __restrict__ bfc,
                                             float* __restrict__ out) {
    int b = blockIdx.x;
    int t = threadIdx.x;
    float a = 0.f;
    for (int j = t; j < 512; j += 64) a += (float)hh[b * 512 + j] * Wfc[j];
#pragma unroll
    for (int o = 32; o; o >>= 1) a += __shfl_down(a, o, 64);
    if (t == 0) out[b] = a + bfc[0];
}

extern "C" void kernel_launch(void* const* d_in, const int* in_sizes, int n_in,
                              void* d_out, int out_size, void* d_ws, size_t ws_size,
                              hipStream_t stream) {
    const float* x   = (const float*)d_in[0];
    const float* Wq  = (const float*)d_in[1];
    const float* bq  = (const float*)d_in[2];
    const float* Wk  = (const float*)d_in[3];
    const float* bk  = (const float*)d_in[4];
    const float* Wv  = (const float*)d_in[5];
    const float* bv  = (const float*)d_in[6];
    const float* Wo  = (const float*)d_in[7];
    const float* bo  = (const float*)d_in[8];
    const float* Wih = (const float*)d_in[9];
    const float* bih = (const float*)d_in[10];
    const float* Whh = (const float*)d_in[11];
    const float* bhh = (const float*)d_in[12];
    const float* Wfc = (const float*)d_in[13];
    const float* bfc = (const float*)d_in[14];
    float* out = (float*)d_out;
    char* base = (char*)d_ws;

    // [0,16M):  x_f16 -> h0 f16 [t][b][512]
    // [32,48M): Q_f16 -> ctx f16
    // [48,64M): K_f16 -> atten_out f16 -> h1 f16 [t][b][512]
    // [64,80M): Vt f16
    // [80,112M): pre f32 [t][b][512] (pre0, then pre1)
    // [112,116M): 6 f16 weights + 2 packed Whh
    _Float16* xh   = (_Float16*)(base);
    _Float16* h0h  = (_Float16*)(base);
    _Float16* Qh   = (_Float16*)(base + ((size_t)32 << 20));
    _Float16* Kh   = (_Float16*)(base + ((size_t)48 << 20));
    _Float16* h1h  = (_Float16*)(base + ((size_t)48 << 20));
    _Float16* Vth  = (_Float16*)(base + ((size_t)64 << 20));
    float*    pre  = (float*)(base + ((size_t)80 << 20));
    _Float16* wgt  = (_Float16*)(base + ((size_t)112 << 20));
    const size_t WSZ = 512 * 512;

    cast_h<<<dim3(4096), dim3(256), 0, stream>>>(x, xh, (B * S * E) / 4);
    cast_h<<<dim3(256), dim3(256), 0, stream>>>(Wq, wgt + 0 * WSZ, WSZ / 4);
    cast_h<<<dim3(256), dim3(256), 0, stream>>>(Wk, wgt + 1 * WSZ, WSZ / 4);
    cast_h<<<dim3(256), dim3(256), 0, stream>>>(Wv, wgt + 2 * WSZ, WSZ / 4);
    cast_h<<<dim3(256), dim3(256), 0, stream>>>(Wo, wgt + 3 * WSZ, WSZ / 4);
    cast_h<<<dim3(256), dim3(256), 0, stream>>>(Wih, wgt + 4 * WSZ, WSZ / 4);
    cast_h<<<dim3(256), dim3(256), 0, stream>>>(Wih + WSZ, wgt + 5 * WSZ, WSZ / 4);
    pack_w<<<dim3(128), dim3(256), 0, stream>>>(Whh, wgt + 6 * WSZ);
    pack_w<<<dim3(128), dim3(256), 0, stream>>>(Whh + WSZ, wgt + 7 * WSZ);

    const dim3 gg(4, 128), blk(256);
    gemm_mfma<1><<<gg, blk, 0, stream>>>(xh, wgt + 0 * WSZ, bq, Qh, B * S, E, E);
    gemm_mfma<1><<<gg, blk, 0, stream>>>(xh, wgt + 1 * WSZ, bk, Kh, B * S, E, E);
    gemm_mfma<2><<<gg, blk, 0, stream>>>(xh, wgt + 2 * WSZ, bv, Vth, B * S, E, E);
    attn_mfma<<<dim3(B * NH * 8), blk, 0, stream>>>(Qh, Kh, Vth);
    gemm_mfma<1><<<gg, blk, 0, stream>>>(Qh, wgt + 3 * WSZ, bo, Kh, B * S, E, E);
    gemm_mfma<3><<<gg, blk, 0, stream>>>(Kh, wgt + 4 * WSZ, bih, pre, B * S, H, E);

    // layer 0 (h0 overwrites x_f16 slab, already consumed)
    rnn_batch<<<dim3(32), dim3(512), 0, stream>>>(pre, wgt + 6 * WSZ, bhh, h0h);
    // layer 1 input projection: pre1 = h0 @ Wih1^T + bih1 (rows already t*32+b)
    gemm_mfma<0><<<gg, blk, 0, stream>>>(h0h, wgt + 5 * WSZ, bih + 512, pre, B * S, H, H);
    // layer 1 (h1 overwrites atten_out slab, already consumed)
    rnn_batch<<<dim3(32), dim3(512), 0, stream>>>(pre, wgt + 7 * WSZ, bhh + 512, h1h);
    fc_out<<<dim3(32), dim3(64), 0, stream>>>(h1h + (size_t)511 * B * H, Wfc, bfc, out);
}

// Round 16
// 2016.927 us; speedup vs baseline: 2.0415x; 2.0415x over previous
//
#include <hip/hip_runtime.h>
#include <hip/hip_fp16.h>

#define B 32
#define S 512
#define E 512
#define H 512
#define NH 8
#define HD 64
#define POISON 0x7FC0DEADu

typedef _Float16 h16x8 __attribute__((ext_vector_type(8)));
typedef _Float16 h16x4 __attribute__((ext_vector_type(4)));
typedef _Float16 h16x2 __attribute__((ext_vector_type(2)));
typedef float f32x4 __attribute__((ext_vector_type(4)));

#if __has_builtin(__builtin_amdgcn_fdot2)
__device__ __forceinline__ float dot2f(h16x2 a, h16x2 b, float c) {
    return __builtin_amdgcn_fdot2(a, b, c, false);
}
#else
__device__ __forceinline__ float dot2f(h16x2 a, h16x2 b, float c) {
    return c + (float)a[0] * (float)b[0] + (float)a[1] * (float)b[1];
}
#endif

__device__ __forceinline__ h16x2 pr(h16x8 v, int q) {
    h16x2 r; r[0] = v[2 * q]; r[1] = v[2 * q + 1]; return r;
}

// ---------------- fp32 -> fp16 cast (vectorized, grid-stride) ----------------
__global__ __launch_bounds__(256) void cast_h(const float* __restrict__ src,
                                              _Float16* __restrict__ dst, int n4) {
    int i = blockIdx.x * 256 + threadIdx.x;
    const int stride = gridDim.x * 256;
    for (; i < n4; i += stride) {
        float4 v = ((const float4*)src)[i];
        h16x4 o;
        o[0] = (_Float16)v.x; o[1] = (_Float16)v.y;
        o[2] = (_Float16)v.z; o[3] = (_Float16)v.w;
        ((h16x4*)dst)[i] = o;
    }
}

// ---------------- MFMA GEMM: C[M,N] = A[M,K] @ W[N,K]^T + bias ----------------
// OMODE 1: f16 row-major. 2: f16 scattered to Vt[(b*8+h)*64+d][s].
// 3: f32 time-major scatter row r=b*512+s -> C[(s*32+b)*N+c].
template <int OMODE>
__global__ __launch_bounds__(256) void gemm_mfma(const _Float16* __restrict__ A,
                                                 const _Float16* __restrict__ W,
                                                 const float* __restrict__ bias,
                                                 void* __restrict__ Cout,
                                                 int M, int N, int K) {
    __shared__ __align__(16) _Float16 Als[128 * 32];
    __shared__ __align__(16) _Float16 Bls[128 * 32];
    const int tid = threadIdx.x;
    const int m0 = blockIdx.y * 128;
    const int n0 = blockIdx.x * 128;
    const int lane = tid & 63;
    const int w = tid >> 6;
    const int wm = w >> 1, wn = w & 1;
    f32x4 acc[4][4] = {};

    const int srow = tid >> 1;
    const int shalf = tid & 1;
    const _Float16* Ag = A + (size_t)(m0 + srow) * K + shalf * 16;
    const _Float16* Wg = W + (size_t)(n0 + srow) * K + shalf * 16;

    for (int k0 = 0; k0 < K; k0 += 32) {
        h16x8 a0 = *(const h16x8*)(Ag + k0);
        h16x8 a1 = *(const h16x8*)(Ag + k0 + 8);
        h16x8 b0 = *(const h16x8*)(Wg + k0);
        h16x8 b1 = *(const h16x8*)(Wg + k0 + 8);
        __syncthreads();
        *(h16x8*)&Als[srow * 32 + shalf * 16] = a0;
        *(h16x8*)&Als[srow * 32 + shalf * 16 + 8] = a1;
        *(h16x8*)&Bls[srow * 32 + shalf * 16] = b0;
        *(h16x8*)&Bls[srow * 32 + shalf * 16 + 8] = b1;
        __syncthreads();
        h16x8 af[4], bf[4];
#pragma unroll
        for (int mt = 0; mt < 4; ++mt)
            af[mt] = *(const h16x8*)&Als[(wm * 64 + mt * 16 + (lane & 15)) * 32 + (lane >> 4) * 8];
#pragma unroll
        for (int nt = 0; nt < 4; ++nt)
            bf[nt] = *(const h16x8*)&Bls[(wn * 64 + nt * 16 + (lane & 15)) * 32 + (lane >> 4) * 8];
#pragma unroll
        for (int mt = 0; mt < 4; ++mt)
#pragma unroll
            for (int nt = 0; nt < 4; ++nt)
                acc[mt][nt] = __builtin_amdgcn_mfma_f32_16x16x32_f16(af[mt], bf[nt], acc[mt][nt], 0, 0, 0);
    }

    float* Cf = (float*)Cout;
    _Float16* Ch = (_Float16*)Cout;
    const int colb = n0 + wn * 64 + (lane & 15);
    const int rowb = m0 + wm * 64 + ((lane >> 4) << 2);
#pragma unroll
    for (int mt = 0; mt < 4; ++mt) {
#pragma unroll
        for (int nt = 0; nt < 4; ++nt) {
            const int c = colb + nt * 16;
            const float bv = bias[c];
            if (OMODE == 2) {
                const int R0 = rowb + mt * 16;
                const int bb = R0 >> 9, s = R0 & 511, hh = c >> 6, d = c & 63;
                h16x4 pk;
#pragma unroll
                for (int j = 0; j < 4; ++j) pk[j] = (_Float16)(acc[mt][nt][j] + bv);
                *(h16x4*)&Ch[((size_t)(bb * 8 + hh) * 64 + d) * 512 + s] = pk;
            } else {
#pragma unroll
                for (int j = 0; j < 4; ++j) {
                    const int R = rowb + mt * 16 + j;
                    const float v = acc[mt][nt][j] + bv;
                    if (OMODE == 3) Cf[((size_t)(R & 511) * 32 + (R >> 9)) * N + c] = v;
                    else Ch[(size_t)R * N + c] = (_Float16)v;
                }
            }
        }
    }
}

// ---------------- MFMA flash attention: per (b, h, 64-row q-tile) ----------------
__global__ __launch_bounds__(256) void attn_mfma(_Float16* __restrict__ Qb,
                                                 const _Float16* __restrict__ Kb,
                                                 const _Float16* __restrict__ Vt) {
    __shared__ __align__(16) _Float16 Qs[64 * 72];
    __shared__ __align__(16) _Float16 Ks[64 * 72];
    __shared__ __align__(16) _Float16 Vs[64 * 72];
    __shared__ __align__(16) _Float16 Ps[4 * 16 * 72];
    const int tid = threadIdx.x;
    const int lane = tid & 63;
    const int w = tid >> 6;
    const int qt = blockIdx.x & 7;
    const int h = (blockIdx.x >> 3) & 7;
    const int b = blockIdx.x >> 6;
    const size_t qrow0 = (size_t)b * 512 + qt * 64;
    const int col0 = h * 64;

    {
        const int r = tid >> 2;
        const int c0 = (tid & 3) << 4;
        const _Float16* gq = &Qb[(qrow0 + r) * 512 + col0 + c0];
        *(h16x8*)&Qs[r * 72 + c0] = *(const h16x8*)(gq);
        *(h16x8*)&Qs[r * 72 + c0 + 8] = *(const h16x8*)(gq + 8);
    }
    __syncthreads();
    h16x8 aq[2];
#pragma unroll
    for (int ks = 0; ks < 2; ++ks)
        aq[ks] = *(const h16x8*)&Qs[(w * 16 + (lane & 15)) * 72 + ks * 32 + (lane >> 4) * 8];

    float m[4] = {-1e30f, -1e30f, -1e30f, -1e30f};
    float l[4] = {0.f, 0.f, 0.f, 0.f};
    f32x4 acco[4] = {};

    for (int kt = 0; kt < 8; ++kt) {
        __syncthreads();
        {
            const int r = tid >> 2;
            const int c0 = (tid & 3) << 4;
            const _Float16* gk = &Kb[((size_t)b * 512 + kt * 64 + r) * 512 + col0 + c0];
            *(h16x8*)&Ks[r * 72 + c0] = *(const h16x8*)(gk);
            *(h16x8*)&Ks[r * 72 + c0 + 8] = *(const h16x8*)(gk + 8);
            const _Float16* gv = &Vt[((size_t)(b * 8 + h) * 64 + r) * 512 + kt * 64 + c0];
            *(h16x8*)&Vs[r * 72 + c0] = *(const h16x8*)(gv);
            *(h16x8*)&Vs[r * 72 + c0 + 8] = *(const h16x8*)(gv + 8);
        }
        __syncthreads();
        f32x4 accs[4] = {};
#pragma unroll
        for (int nt = 0; nt < 4; ++nt) {
#pragma unroll
            for (int ks = 0; ks < 2; ++ks) {
                h16x8 bk = *(const h16x8*)&Ks[(nt * 16 + (lane & 15)) * 72 + ks * 32 + (lane >> 4) * 8];
                accs[nt] = __builtin_amdgcn_mfma_f32_16x16x32_f16(aq[ks], bk, accs[nt], 0, 0, 0);
            }
        }
#pragma unroll
        for (int j = 0; j < 4; ++j) {
            float v = fmaxf(fmaxf(accs[0][j], accs[1][j]), fmaxf(accs[2][j], accs[3][j]));
#pragma unroll
            for (int o = 1; o < 16; o <<= 1) v = fmaxf(v, __shfl_xor(v, o, 64));
            const float mn = fmaxf(m[j], v);
            const float scl = __expf(0.125f * (m[j] - mn));
            m[j] = mn;
            l[j] *= scl;
#pragma unroll
            for (int nt2 = 0; nt2 < 4; ++nt2) acco[nt2][j] *= scl;
            float ps = 0.f;
            const int prow = ((lane >> 4) << 2) + j;
#pragma unroll
            for (int nt = 0; nt < 4; ++nt) {
                const float p = __expf(0.125f * (accs[nt][j] - mn));
                ps += p;
                Ps[w * 16 * 72 + prow * 72 + nt * 16 + (lane & 15)] = (_Float16)p;
            }
#pragma unroll
            for (int o = 1; o < 16; o <<= 1) ps += __shfl_xor(ps, o, 64);
            l[j] += ps;
        }
        __syncthreads();
#pragma unroll
        for (int ks2 = 0; ks2 < 2; ++ks2) {
            h16x8 pa = *(const h16x8*)&Ps[w * 16 * 72 + (lane & 15) * 72 + ks2 * 32 + (lane >> 4) * 8];
#pragma unroll
            for (int nt2 = 0; nt2 < 4; ++nt2) {
                h16x8 bv = *(const h16x8*)&Vs[(nt2 * 16 + (lane & 15)) * 72 + ks2 * 32 + (lane >> 4) * 8];
                acco[nt2] = __builtin_amdgcn_mfma_f32_16x16x32_f16(pa, bv, acco[nt2], 0, 0, 0);
            }
        }
    }
#pragma unroll
    for (int j = 0; j < 4; ++j) {
        const float inv = 1.0f / l[j];
        const size_t r = qrow0 + w * 16 + ((lane >> 4) << 2) + j;
#pragma unroll
        for (int nt2 = 0; nt2 < 4; ++nt2)
            Qb[r * 512 + col0 + nt2 * 16 + (lane & 15)] = (_Float16)(acco[nt2][j] * inv);
    }
}

// ---------------- poison fill ----------------
__global__ __launch_bounds__(256) void fill_poison(uint4* __restrict__ p, int n) {
    const uint4 v = {POISON, POISON, POISON, POISON};
    int i = blockIdx.x * 256 + threadIdx.x;
    const int st = gridDim.x * 256;
    for (; i < n; i += st) p[i] = v;
}

__device__ __forceinline__ unsigned long long poll2(const unsigned* p) {
    unsigned long long v = __hip_atomic_load((const unsigned long long*)p,
                                             __ATOMIC_RELAXED, __HIP_MEMORY_SCOPE_AGENT);
    while ((unsigned)v == POISON || (unsigned)(v >> 32) == POISON) {
        __builtin_amdgcn_s_sleep(1);
        v = __hip_atomic_load((const unsigned long long*)p,
                              __ATOMIC_RELAXED, __HIP_MEMORY_SCOPE_AGENT);
    }
    return v;
}

// ---------------- fused 2-layer persistent RNN: 512 blocks, 2/CU resident ----------
// role = bid>>8 (0: L0, 1: L1); b = bid&31; sl = (bid>>5)&7. Round-12 step verbatim.
// LDS Wl[64][520] fp16 holds role-specific weights (L0: Whh0 slice; L1: Wih1 slice);
// row stride 260 words == 4 banks -> the 16 jq-lanes spread over 8 bank-groups
// (2/bank = free). L1 streams Whh1 from L2 (64KB/step, issued under the polls).
// Sync: poison-poll dataflow only (1 u64/thread), no fences, no counters.
__global__ __launch_bounds__(256, 2) void rnn_fused(const float* __restrict__ pre0,
                                                    const _Float16* __restrict__ Whh0h,
                                                    const _Float16* __restrict__ Whh1h,
                                                    const _Float16* __restrict__ Wih1h,
                                                    const float* __restrict__ bhh,
                                                    const float* __restrict__ bih,
                                                    unsigned* __restrict__ h0u,
                                                    unsigned* __restrict__ h1u) {
    __shared__ __align__(16) _Float16 Wl[64 * 520];   // 66.56 KB
    __shared__ float hl[512];
    __shared__ float hl0[512];
    __shared__ float part[64][17];
    const int tid = threadIdx.x;
    const int role = blockIdx.x >> 8;
    const int b = blockIdx.x & 31;
    const int sl = (blockIdx.x >> 5) & 7;
    const int jq = tid & 15, kg = tid >> 4;
    const int jbase = sl * 64, k0 = kg * 32;
    const int j64 = tid & 63;

    {   // stage role-specific LDS weights (once)
        const _Float16* src = role ? Wih1h : Whh0h;
#pragma unroll
        for (int i = 0; i < 16; ++i) {
            const int e = tid + i * 256;
            const int row = e >> 6, l = e & 63;
            *(h16x8*)&Wl[row * 520 + l * 8] =
                *(const h16x8*)&src[(size_t)(jbase + row) * 512 + l * 8];
        }
    }
    const float bconst = role ? (bih[512 + jbase + j64] + bhh[512 + jbase + j64])
                              : bhh[jbase + j64];
    unsigned* myH = role ? h1u : h0u;
    const _Float16* wp0 = Whh1h + (size_t)(jbase + jq * 4 + 0) * 512 + k0;
    const _Float16* wp1 = Whh1h + (size_t)(jbase + jq * 4 + 1) * 512 + k0;
    const _Float16* wp2 = Whh1h + (size_t)(jbase + jq * 4 + 2) * 512 + k0;
    const _Float16* wp3 = Whh1h + (size_t)(jbase + jq * 4 + 3) * 512 + k0;
    __syncthreads();

    for (int t = 0; t < S; ++t) {
        // LDS weight fragments (static content): issue before any poll
        h16x8 wl0[4], wl1[4], wl2[4], wl3[4];
#pragma unroll
        for (int c8 = 0; c8 < 4; ++c8) {
            const int off = k0 + c8 * 8;
            wl0[c8] = *(const h16x8*)&Wl[(jq * 4 + 0) * 520 + off];
            wl1[c8] = *(const h16x8*)&Wl[(jq * 4 + 1) * 520 + off];
            wl2[c8] = *(const h16x8*)&Wl[(jq * 4 + 2) * 520 + off];
            wl3[c8] = *(const h16x8*)&Wl[(jq * 4 + 3) * 520 + off];
        }
        float a0 = 0.f, a1 = 0.f, a2 = 0.f, a3 = 0.f;
        float pv = 0.f;
        if (role == 0) {
            pv = pre0[((size_t)t * 32 + b) * 512 + jbase + j64];
            if (t > 0) {
                const unsigned long long v =
                    poll2(h0u + (size_t)(t - 1) * (B * H) + b * H + tid * 2);
                hl[tid * 2] = __uint_as_float((unsigned)v);
                hl[tid * 2 + 1] = __uint_as_float((unsigned)(v >> 32));
                __syncthreads();
                f32x4 hw[8];
#pragma unroll
                for (int c = 0; c < 8; ++c) hw[c] = *(const f32x4*)&hl[k0 + c * 4];
                h16x2 hp[16];
#pragma unroll
                for (int c = 0; c < 8; ++c) {
                    h16x2 p0, p1;
                    p0[0] = (_Float16)hw[c][0]; p0[1] = (_Float16)hw[c][1];
                    p1[0] = (_Float16)hw[c][2]; p1[1] = (_Float16)hw[c][3];
                    hp[2 * c] = p0; hp[2 * c + 1] = p1;
                }
#pragma unroll
                for (int c8 = 0; c8 < 4; ++c8) {
#pragma unroll
                    for (int q = 0; q < 4; ++q) {
                        a0 = dot2f(pr(wl0[c8], q), hp[c8 * 4 + q], a0);
                        a1 = dot2f(pr(wl1[c8], q), hp[c8 * 4 + q], a1);
                        a2 = dot2f(pr(wl2[c8], q), hp[c8 * 4 + q], a2);
                        a3 = dot2f(pr(wl3[c8], q), hp[c8 * 4 + q], a3);
                    }
                }
            }
        } else {
            // poll h0[t] (L0 runs ahead; usually ready)
            const unsigned long long v0 =
                poll2(h0u + (size_t)t * (B * H) + b * H + tid * 2);
            hl0[tid * 2] = __uint_as_float((unsigned)v0);
            hl0[tid * 2 + 1] = __uint_as_float((unsigned)(v0 >> 32));
            // stream Whh1 (in flight across the barrier + wih compute)
            h16x8 ws0[4], ws1[4], ws2[4], ws3[4];
#pragma unroll
            for (int c8 = 0; c8 < 4; ++c8) {
                ws0[c8] = *(const h16x8*)(wp0 + c8 * 8);
                ws1[c8] = *(const h16x8*)(wp1 + c8 * 8);
                ws2[c8] = *(const h16x8*)(wp2 + c8 * 8);
                ws3[c8] = *(const h16x8*)(wp3 + c8 * 8);
            }
            __syncthreads();
            {   // pre1 contribution: Wih1 (LDS) . h0[t]
                f32x4 hw[8];
#pragma unroll
                for (int c = 0; c < 8; ++c) hw[c] = *(const f32x4*)&hl0[k0 + c * 4];
                h16x2 hp[16];
#pragma unroll
                for (int c = 0; c < 8; ++c) {
                    h16x2 p0, p1;
                    p0[0] = (_Float16)hw[c][0]; p0[1] = (_Float16)hw[c][1];
                    p1[0] = (_Float16)hw[c][2]; p1[1] = (_Float16)hw[c][3];
                    hp[2 * c] = p0; hp[2 * c + 1] = p1;
                }
#pragma unroll
                for (int c8 = 0; c8 < 4; ++c8) {
#pragma unroll
                    for (int q = 0; q < 4; ++q) {
                        a0 = dot2f(pr(wl0[c8], q), hp[c8 * 4 + q], a0);
                        a1 = dot2f(pr(wl1[c8], q), hp[c8 * 4 + q], a1);
                        a2 = dot2f(pr(wl2[c8], q), hp[c8 * 4 + q], a2);
                        a3 = dot2f(pr(wl3[c8], q), hp[c8 * 4 + q], a3);
                    }
                }
            }
            if (t > 0) {
                const unsigned long long v =
                    poll2(h1u + (size_t)(t - 1) * (B * H) + b * H + tid * 2);
                hl[tid * 2] = __uint_as_float((unsigned)v);
                hl[tid * 2 + 1] = __uint_as_float((unsigned)(v >> 32));
                __syncthreads();
                f32x4 hw[8];
#pragma unroll
                for (int c = 0; c < 8; ++c) hw[c] = *(const f32x4*)&hl[k0 + c * 4];
                h16x2 hp[16];
#pragma unroll
                for (int c = 0; c < 8; ++c) {
                    h16x2 p0, p1;
                    p0[0] = (_Float16)hw[c][0]; p0[1] = (_Float16)hw[c][1];
                    p1[0] = (_Float16)hw[c][2]; p1[1] = (_Float16)hw[c][3];
                    hp[2 * c] = p0; hp[2 * c + 1] = p1;
                }
#pragma unroll
                for (int c8 = 0; c8 < 4; ++c8) {
#pragma unroll
                    for (int q = 0; q < 4; ++q) {
                        a0 = dot2f(pr(ws0[c8], q), hp[c8 * 4 + q], a0);
                        a1 = dot2f(pr(ws1[c8], q), hp[c8 * 4 + q], a1);
                        a2 = dot2f(pr(ws2[c8], q), hp[c8 * 4 + q], a2);
                        a3 = dot2f(pr(ws3[c8], q), hp[c8 * 4 + q], a3);
                    }
                }
            }
        }
        part[jq * 4 + 0][kg] = a0;
        part[jq * 4 + 1][kg] = a1;
        part[jq * 4 + 2][kg] = a2;
        part[jq * 4 + 3][kg] = a3;
        __syncthreads();
        if (tid < 64) {
            float s2 = 0.f;
#pragma unroll
            for (int i = 0; i < 16; ++i) s2 += part[tid][i];
            s2 += bconst + pv;
            s2 = fminf(fmaxf(s2, -15.f), 15.f);
            const float ex = __expf(2.f * s2);
            const float hval = (ex - 1.f) / (ex + 1.f);
            __hip_atomic_store(&myH[(size_t)t * (B * H) + b * H + jbase + tid],
                               __float_as_uint(hval), __ATOMIC_RELAXED,
                               __HIP_MEMORY_SCOPE_AGENT);
        }
        __syncthreads();
    }
}

// ---------------- final FC: out[b] = h1[511][b,:] . Wfc[0,:] + bfc[0] ----------------
__global__ __launch_bounds__(64) void fc_out(const unsigned* __restrict__ hbits,
                                             const float* __restrict__ Wfc,
                                             const float* __restrict__ bfc,
                                             float* __restrict__ out) {
    int b = blockIdx.x;
    int t = threadIdx.x;
    float a = 0.f;
    for (int j = t; j < 512; j += 64) a += __uint_as_float(hbits[b * 512 + j]) * Wfc[j];
#pragma unroll
    for (int o = 32; o; o >>= 1) a += __shfl_down(a, o, 64);
    if (t == 0) out[b] = a + bfc[0];
}

extern "C" void kernel_launch(void* const* d_in, const int* in_sizes, int n_in,
                              void* d_out, int out_size, void* d_ws, size_t ws_size,
                              hipStream_t stream) {
    const float* x   = (const float*)d_in[0];
    const float* Wq  = (const float*)d_in[1];
    const float* bq  = (const float*)d_in[2];
    const float* Wk  = (const float*)d_in[3];
    const float* bk  = (const float*)d_in[4];
    const float* Wv  = (const float*)d_in[5];
    const float* bv  = (const float*)d_in[6];
    const float* Wo  = (const float*)d_in[7];
    const float* bo  = (const float*)d_in[8];
    const float* Wih = (const float*)d_in[9];
    const float* bih = (const float*)d_in[10];
    const float* Whh = (const float*)d_in[11];
    const float* bhh = (const float*)d_in[12];
    const float* Wfc = (const float*)d_in[13];
    const float* bfc = (const float*)d_in[14];
    float* out = (float*)d_out;
    char* base = (char*)d_ws;

    // [0,32M):  x_f16 -> h0 u32 slab
    // [32,48M): Q_f16 -> ctx f16
    // [48,80M): K_f16 / Vt f16 -> h1 u32 slab
    // [80,112M): pre0 f32 [t][b][512]
    // [112,116M): 8 fp16 weight slices
    _Float16* xh   = (_Float16*)(base);
    unsigned* h0u  = (unsigned*)(base);
    _Float16* Qh   = (_Float16*)(base + ((size_t)32 << 20));
    _Float16* Kh   = (_Float16*)(base + ((size_t)48 << 20));
    unsigned* h1u  = (unsigned*)(base + ((size_t)48 << 20));
    _Float16* Vth  = (_Float16*)(base + ((size_t)64 << 20));
    float*    pre  = (float*)(base + ((size_t)80 << 20));
    _Float16* wgt  = (_Float16*)(base + ((size_t)112 << 20));
    const size_t WSZ = 512 * 512;

    cast_h<<<dim3(4096), dim3(256), 0, stream>>>(x, xh, (B * S * E) / 4);
    cast_h<<<dim3(256), dim3(256), 0, stream>>>(Wq, wgt + 0 * WSZ, WSZ / 4);
    cast_h<<<dim3(256), dim3(256), 0, stream>>>(Wk, wgt + 1 * WSZ, WSZ / 4);
    cast_h<<<dim3(256), dim3(256), 0, stream>>>(Wv, wgt + 2 * WSZ, WSZ / 4);
    cast_h<<<dim3(256), dim3(256), 0, stream>>>(Wo, wgt + 3 * WSZ, WSZ / 4);
    cast_h<<<dim3(256), dim3(256), 0, stream>>>(Wih, wgt + 4 * WSZ, WSZ / 4);
    cast_h<<<dim3(256), dim3(256), 0, stream>>>(Wih + WSZ, wgt + 5 * WSZ, WSZ / 4);
    cast_h<<<dim3(256), dim3(256), 0, stream>>>(Whh, wgt + 6 * WSZ, WSZ / 4);
    cast_h<<<dim3(256), dim3(256), 0, stream>>>(Whh + WSZ, wgt + 7 * WSZ, WSZ / 4);

    const dim3 gg(4, 128), blk(256);
    gemm_mfma<1><<<gg, blk, 0, stream>>>(xh, wgt + 0 * WSZ, bq, Qh, B * S, E, E);
    gemm_mfma<1><<<gg, blk, 0, stream>>>(xh, wgt + 1 * WSZ, bk, Kh, B * S, E, E);
    gemm_mfma<2><<<gg, blk, 0, stream>>>(xh, wgt + 2 * WSZ, bv, Vth, B * S, E, E);
    attn_mfma<<<dim3(B * NH * 8), blk, 0, stream>>>(Qh, Kh, Vth);
    gemm_mfma<1><<<gg, blk, 0, stream>>>(Qh, wgt + 3 * WSZ, bo, Kh, B * S, E, E);
    gemm_mfma<3><<<gg, blk, 0, stream>>>(Kh, wgt + 4 * WSZ, bih, pre, B * S, H, E);

    // poison both h slabs, then the fused 2-layer RNN (512 blocks, 2/CU resident)
    fill_poison<<<dim3(1024), blk, 0, stream>>>((uint4*)base, (32 << 20) / 16);
    fill_poison<<<dim3(1024), blk, 0, stream>>>((uint4*)(base + ((size_t)48 << 20)),
                                                (32 << 20) / 16);
    rnn_fused<<<dim3(512), blk, 0, stream>>>(pre, wgt + 6 * WSZ, wgt + 7 * WSZ,
                                             wgt + 5 * WSZ, bhh, bih, h0u, h1u);
    fc_out<<<dim3(32), dim3(64), 0, stream>>>(h1u + (size_t)511 * B * H, Wfc, bfc, out);
}

// Round 17
// 1389.963 us; speedup vs baseline: 2.9623x; 1.4511x over previous
//
#include <hip/hip_runtime.h>
#include <hip/hip_fp16.h>

#define B 32
#define S 512
#define E 512
#define H 512
#define NH 8
#define HD 64
#define POISON 0x7FC0DEADu

typedef _Float16 h16x8 __attribute__((ext_vector_type(8)));
typedef _Float16 h16x4 __attribute__((ext_vector_type(4)));
typedef _Float16 h16x2 __attribute__((ext_vector_type(2)));
typedef float f32x4 __attribute__((ext_vector_type(4)));

#if __has_builtin(__builtin_amdgcn_fdot2)
__device__ __forceinline__ float dot2f(h16x2 a, h16x2 b, float c) {
    return __builtin_amdgcn_fdot2(a, b, c, false);
}
#else
__device__ __forceinline__ float dot2f(h16x2 a, h16x2 b, float c) {
    return c + (float)a[0] * (float)b[0] + (float)a[1] * (float)b[1];
}
#endif

__device__ __forceinline__ h16x2 pr(h16x8 v, int q) {
    h16x2 r; r[0] = v[2 * q]; r[1] = v[2 * q + 1]; return r;
}
__device__ __forceinline__ unsigned pack2(float x, float y) {
    unsigned short a = __builtin_bit_cast(unsigned short, (_Float16)x);
    unsigned short b = __builtin_bit_cast(unsigned short, (_Float16)y);
    return ((unsigned)b << 16) | (unsigned)a;
}

// ---------------- fp32 -> fp16 cast (vectorized, grid-stride) ----------------
__global__ __launch_bounds__(256) void cast_h(const float* __restrict__ src,
                                              _Float16* __restrict__ dst, int n4) {
    int i = blockIdx.x * 256 + threadIdx.x;
    const int stride = gridDim.x * 256;
    for (; i < n4; i += stride) {
        float4 v = ((const float4*)src)[i];
        h16x4 o;
        o[0] = (_Float16)v.x; o[1] = (_Float16)v.y;
        o[2] = (_Float16)v.z; o[3] = (_Float16)v.w;
        ((h16x4*)dst)[i] = o;
    }
}

// ---------------- MFMA GEMM: C[M,N] = A[M,K] @ W[N,K]^T + bias ----------------
// OMODE 0: f32 row-major. 1: f16 row-major. 2: f16 scattered to Vt[(b*8+h)*64+d][s].
// 3: f32 time-major scatter row r=b*512+s -> C[(s*32+b)*N+c].
template <int OMODE>
__global__ __launch_bounds__(256) void gemm_mfma(const _Float16* __restrict__ A,
                                                 const _Float16* __restrict__ W,
                                                 const float* __restrict__ bias,
                                                 void* __restrict__ Cout,
                                                 int M, int N, int K) {
    __shared__ __align__(16) _Float16 Als[128 * 32];
    __shared__ __align__(16) _Float16 Bls[128 * 32];
    const int tid = threadIdx.x;
    const int m0 = blockIdx.y * 128;
    const int n0 = blockIdx.x * 128;
    const int lane = tid & 63;
    const int w = tid >> 6;
    const int wm = w >> 1, wn = w & 1;
    f32x4 acc[4][4] = {};

    const int srow = tid >> 1;
    const int shalf = tid & 1;
    const _Float16* Ag = A + (size_t)(m0 + srow) * K + shalf * 16;
    const _Float16* Wg = W + (size_t)(n0 + srow) * K + shalf * 16;

    for (int k0 = 0; k0 < K; k0 += 32) {
        h16x8 a0 = *(const h16x8*)(Ag + k0);
        h16x8 a1 = *(const h16x8*)(Ag + k0 + 8);
        h16x8 b0 = *(const h16x8*)(Wg + k0);
        h16x8 b1 = *(const h16x8*)(Wg + k0 + 8);
        __syncthreads();
        *(h16x8*)&Als[srow * 32 + shalf * 16] = a0;
        *(h16x8*)&Als[srow * 32 + shalf * 16 + 8] = a1;
        *(h16x8*)&Bls[srow * 32 + shalf * 16] = b0;
        *(h16x8*)&Bls[srow * 32 + shalf * 16 + 8] = b1;
        __syncthreads();
        h16x8 af[4], bf[4];
#pragma unroll
        for (int mt = 0; mt < 4; ++mt)
            af[mt] = *(const h16x8*)&Als[(wm * 64 + mt * 16 + (lane & 15)) * 32 + (lane >> 4) * 8];
#pragma unroll
        for (int nt = 0; nt < 4; ++nt)
            bf[nt] = *(const h16x8*)&Bls[(wn * 64 + nt * 16 + (lane & 15)) * 32 + (lane >> 4) * 8];
#pragma unroll
        for (int mt = 0; mt < 4; ++mt)
#pragma unroll
            for (int nt = 0; nt < 4; ++nt)
                acc[mt][nt] = __builtin_amdgcn_mfma_f32_16x16x32_f16(af[mt], bf[nt], acc[mt][nt], 0, 0, 0);
    }

    float* Cf = (float*)Cout;
    _Float16* Ch = (_Float16*)Cout;
    const int colb = n0 + wn * 64 + (lane & 15);
    const int rowb = m0 + wm * 64 + ((lane >> 4) << 2);
#pragma unroll
    for (int mt = 0; mt < 4; ++mt) {
#pragma unroll
        for (int nt = 0; nt < 4; ++nt) {
            const int c = colb + nt * 16;
            const float bv = bias[c];
            if (OMODE == 2) {
                const int R0 = rowb + mt * 16;
                const int bb = R0 >> 9, s = R0 & 511, hh = c >> 6, d = c & 63;
                h16x4 pk;
#pragma unroll
                for (int j = 0; j < 4; ++j) pk[j] = (_Float16)(acc[mt][nt][j] + bv);
                *(h16x4*)&Ch[((size_t)(bb * 8 + hh) * 64 + d) * 512 + s] = pk;
            } else {
#pragma unroll
                for (int j = 0; j < 4; ++j) {
                    const int R = rowb + mt * 16 + j;
                    const float v = acc[mt][nt][j] + bv;
                    if (OMODE == 0) Cf[(size_t)R * N + c] = v;
                    else if (OMODE == 3) Cf[((size_t)(R & 511) * 32 + (R >> 9)) * N + c] = v;
                    else Ch[(size_t)R * N + c] = (_Float16)v;
                }
            }
        }
    }
}

// ---------------- MFMA flash attention: per (b, h, 64-row q-tile) ----------------
__global__ __launch_bounds__(256) void attn_mfma(_Float16* __restrict__ Qb,
                                                 const _Float16* __restrict__ Kb,
                                                 const _Float16* __restrict__ Vt) {
    __shared__ __align__(16) _Float16 Qs[64 * 72];
    __shared__ __align__(16) _Float16 Ks[64 * 72];
    __shared__ __align__(16) _Float16 Vs[64 * 72];
    __shared__ __align__(16) _Float16 Ps[4 * 16 * 72];
    const int tid = threadIdx.x;
    const int lane = tid & 63;
    const int w = tid >> 6;
    const int qt = blockIdx.x & 7;
    const int h = (blockIdx.x >> 3) & 7;
    const int b = blockIdx.x >> 6;
    const size_t qrow0 = (size_t)b * 512 + qt * 64;
    const int col0 = h * 64;

    {
        const int r = tid >> 2;
        const int c0 = (tid & 3) << 4;
        const _Float16* gq = &Qb[(qrow0 + r) * 512 + col0 + c0];
        *(h16x8*)&Qs[r * 72 + c0] = *(const h16x8*)(gq);
        *(h16x8*)&Qs[r * 72 + c0 + 8] = *(const h16x8*)(gq + 8);
    }
    __syncthreads();
    h16x8 aq[2];
#pragma unroll
    for (int ks = 0; ks < 2; ++ks)
        aq[ks] = *(const h16x8*)&Qs[(w * 16 + (lane & 15)) * 72 + ks * 32 + (lane >> 4) * 8];

    float m[4] = {-1e30f, -1e30f, -1e30f, -1e30f};
    float l[4] = {0.f, 0.f, 0.f, 0.f};
    f32x4 acco[4] = {};

    for (int kt = 0; kt < 8; ++kt) {
        __syncthreads();
        {
            const int r = tid >> 2;
            const int c0 = (tid & 3) << 4;
            const _Float16* gk = &Kb[((size_t)b * 512 + kt * 64 + r) * 512 + col0 + c0];
            *(h16x8*)&Ks[r * 72 + c0] = *(const h16x8*)(gk);
            *(h16x8*)&Ks[r * 72 + c0 + 8] = *(const h16x8*)(gk + 8);
            const _Float16* gv = &Vt[((size_t)(b * 8 + h) * 64 + r) * 512 + kt * 64 + c0];
            *(h16x8*)&Vs[r * 72 + c0] = *(const h16x8*)(gv);
            *(h16x8*)&Vs[r * 72 + c0 + 8] = *(const h16x8*)(gv + 8);
        }
        __syncthreads();
        f32x4 accs[4] = {};
#pragma unroll
        for (int nt = 0; nt < 4; ++nt) {
#pragma unroll
            for (int ks = 0; ks < 2; ++ks) {
                h16x8 bk = *(const h16x8*)&Ks[(nt * 16 + (lane & 15)) * 72 + ks * 32 + (lane >> 4) * 8];
                accs[nt] = __builtin_amdgcn_mfma_f32_16x16x32_f16(aq[ks], bk, accs[nt], 0, 0, 0);
            }
        }
#pragma unroll
        for (int j = 0; j < 4; ++j) {
            float v = fmaxf(fmaxf(accs[0][j], accs[1][j]), fmaxf(accs[2][j], accs[3][j]));
#pragma unroll
            for (int o = 1; o < 16; o <<= 1) v = fmaxf(v, __shfl_xor(v, o, 64));
            const float mn = fmaxf(m[j], v);
            const float scl = __expf(0.125f * (m[j] - mn));
            m[j] = mn;
            l[j] *= scl;
#pragma unroll
            for (int nt2 = 0; nt2 < 4; ++nt2) acco[nt2][j] *= scl;
            float ps = 0.f;
            const int prow = ((lane >> 4) << 2) + j;
#pragma unroll
            for (int nt = 0; nt < 4; ++nt) {
                const float p = __expf(0.125f * (accs[nt][j] - mn));
                ps += p;
                Ps[w * 16 * 72 + prow * 72 + nt * 16 + (lane & 15)] = (_Float16)p;
            }
#pragma unroll
            for (int o = 1; o < 16; o <<= 1) ps += __shfl_xor(ps, o, 64);
            l[j] += ps;
        }
        __syncthreads();
#pragma unroll
        for (int ks2 = 0; ks2 < 2; ++ks2) {
            h16x8 pa = *(const h16x8*)&Ps[w * 16 * 72 + (lane & 15) * 72 + ks2 * 32 + (lane >> 4) * 8];
#pragma unroll
            for (int nt2 = 0; nt2 < 4; ++nt2) {
                h16x8 bv = *(const h16x8*)&Vs[(nt2 * 16 + (lane & 15)) * 72 + ks2 * 32 + (lane >> 4) * 8];
                acco[nt2] = __builtin_amdgcn_mfma_f32_16x16x32_f16(pa, bv, acco[nt2], 0, 0, 0);
            }
        }
    }
#pragma unroll
    for (int j = 0; j < 4; ++j) {
        const float inv = 1.0f / l[j];
        const size_t r = qrow0 + w * 16 + ((lane >> 4) << 2) + j;
#pragma unroll
        for (int nt2 = 0; nt2 < 4; ++nt2)
            Qb[r * 512 + col0 + nt2 * 16 + (lane & 15)] = (_Float16)(acco[nt2][j] * inv);
    }
}

// ---------------- poison fill ----------------
__global__ __launch_bounds__(256) void fill_poison(uint4* __restrict__ p, int n) {
    const uint4 v = {POISON, POISON, POISON, POISON};
    int i = blockIdx.x * 256 + threadIdx.x;
    const int st = gridDim.x * 256;
    for (; i < n; i += st) p[i] = v;
}

// ---------------- persistent single-layer RNN (256 blocks = 32 b x 8 slices) --------
// Round-12 topology; step restructured:
//  - jq = tid>>4, kg = tid&15: k-reduction in low lane bits -> shfl_xor, 1 barrier/step
//  - h published as packed 2xfp16 per u32 (tanh can't alias the poison halves);
//    the same buffer feeds the next layer's GEMM and fc directly
//  - hl redistribute uses a bank-engineered physical layout:
//    logical u32 L at phys (c<<6)+(kg<<2)+i  -> uint4 reads map lanes to banks 4*kg
//  - fp16 weights streamed from L2, prefetched before the poll (round-12 mechanism)
__global__ __launch_bounds__(256) void rnn_persist(const float* __restrict__ pre,
                                                   const _Float16* __restrict__ W16,
                                                   const float* __restrict__ bhh,
                                                   unsigned* __restrict__ hu) {
    __shared__ unsigned hl[2][256];
    const int tid = threadIdx.x;
    const int b = blockIdx.x & 31;
    const int sl = blockIdx.x >> 5;
    const int jq = tid >> 4;          // 0..15 -> j block jq*4..+3
    const int kg = tid & 15;          // 0..15 -> k window [kg*32, +32)
    const int jbase = sl * 64;
    const int j0 = jq * 4;
    const int k0 = kg * 32;

    const _Float16* wp0 = W16 + (size_t)(jbase + j0 + 0) * 512 + k0;
    const _Float16* wp1 = W16 + (size_t)(jbase + j0 + 1) * 512 + k0;
    const _Float16* wp2 = W16 + (size_t)(jbase + j0 + 2) * 512 + k0;
    const _Float16* wp3 = W16 + (size_t)(jbase + j0 + 3) * 512 + k0;
    float4 bj = {0.f, 0.f, 0.f, 0.f};
    if (kg == 0) bj = *(const float4*)&bhh[jbase + j0];

    // scatter indices for the hl physical layout (computed once)
    const int scat = (((tid >> 2) & 3) << 6) + ((tid >> 4) << 2) + (tid & 3);

    for (int t = 0; t < S; ++t) {
        // prefetch weights + pre BEFORE the poll (they fly during the spin)
        h16x8 w0[4], w1[4], w2[4], w3[4];
#pragma unroll
        for (int c8 = 0; c8 < 4; ++c8) {
            w0[c8] = *(const h16x8*)(wp0 + c8 * 8);
            w1[c8] = *(const h16x8*)(wp1 + c8 * 8);
            w2[c8] = *(const h16x8*)(wp2 + c8 * 8);
            w3[c8] = *(const h16x8*)(wp3 + c8 * 8);
        }
        float4 pv = {0.f, 0.f, 0.f, 0.f};
        if (kg == 0) pv = *(const float4*)&pre[((size_t)t * 32 + b) * 512 + jbase + j0];
        const int buf = t & 1;
        if (t > 0) {
            const unsigned* src = hu + (size_t)(t - 1) * (B * H / 2) + b * 256;
            unsigned v = __hip_atomic_load(src + tid, __ATOMIC_RELAXED,
                                           __HIP_MEMORY_SCOPE_AGENT);
            while ((v & 0xFFFFu) == (POISON & 0xFFFFu) && v == POISON) {
                __builtin_amdgcn_s_sleep(1);
                v = __hip_atomic_load(src + tid, __ATOMIC_RELAXED,
                                      __HIP_MEMORY_SCOPE_AGENT);
            }
            while (v == POISON) {   // safety: exact-match poison retry
                __builtin_amdgcn_s_sleep(1);
                v = __hip_atomic_load(src + tid, __ATOMIC_RELAXED,
                                      __HIP_MEMORY_SCOPE_AGENT);
            }
            hl[buf][scat] = v;
        }
        __syncthreads();
        float a0 = 0.f, a1 = 0.f, a2 = 0.f, a3 = 0.f;
        if (t > 0) {
            const uint4* h4 = (const uint4*)hl[buf];
#pragma unroll
            for (int c = 0; c < 4; ++c) {
                const uint4 u = h4[(c << 4) + kg];
                const h16x8 hx = __builtin_bit_cast(h16x8, u);
#pragma unroll
                for (int q = 0; q < 4; ++q) {
                    const h16x2 hq = pr(hx, q);
                    a0 = dot2f(pr(w0[c], q), hq, a0);
                    a1 = dot2f(pr(w1[c], q), hq, a1);
                    a2 = dot2f(pr(w2[c], q), hq, a2);
                    a3 = dot2f(pr(w3[c], q), hq, a3);
                }
            }
        }
#pragma unroll
        for (int o = 1; o < 16; o <<= 1) {
            a0 += __shfl_xor(a0, o, 16);
            a1 += __shfl_xor(a1, o, 16);
            a2 += __shfl_xor(a2, o, 16);
            a3 += __shfl_xor(a3, o, 16);
        }
        if (kg == 0) {
            float s0 = a0 + pv.x + bj.x;
            float s1 = a1 + pv.y + bj.y;
            float s2 = a2 + pv.z + bj.z;
            float s3 = a3 + pv.w + bj.w;
            s0 = fminf(fmaxf(s0, -15.f), 15.f);
            s1 = fminf(fmaxf(s1, -15.f), 15.f);
            s2 = fminf(fmaxf(s2, -15.f), 15.f);
            s3 = fminf(fmaxf(s3, -15.f), 15.f);
            const float e0 = __expf(2.f * s0), e1 = __expf(2.f * s1);
            const float e2 = __expf(2.f * s2), e3 = __expf(2.f * s3);
            uint2 st;
            st.x = pack2((e0 - 1.f) / (e0 + 1.f), (e1 - 1.f) / (e1 + 1.f));
            st.y = pack2((e2 - 1.f) / (e2 + 1.f), (e3 - 1.f) / (e3 + 1.f));
            // plain 8B store: per-dword atomicity + per-u32 poison check suffice
            *(uint2*)&hu[(size_t)t * (B * H / 2) + b * 256 + (jbase + j0) / 2] = st;
        }
    }
}

// ---------------- final FC: out[b] = h1[511][b,:] . Wfc[0,:] + bfc[0] ----------------
__global__ __launch_bounds__(64) void fc_out(const _Float16* __restrict__ hh,
                                             const float* __restrict__ Wfc,
                                             const float* __restrict__ bfc,
                                             float* __restrict__ out) {
    int b = blockIdx.x;
    int t = threadIdx.x;
    float a = 0.f;
    for (int j = t; j < 512; j += 64) a += (float)hh[b * 512 + j] * Wfc[j];
#pragma unroll
    for (int o = 32; o; o >>= 1) a += __shfl_down(a, o, 64);
    if (t == 0) out[b] = a + bfc[0];
}

extern "C" void kernel_launch(void* const* d_in, const int* in_sizes, int n_in,
                              void* d_out, int out_size, void* d_ws, size_t ws_size,
                              hipStream_t stream) {
    const float* x   = (const float*)d_in[0];
    const float* Wq  = (const float*)d_in[1];
    const float* bq  = (const float*)d_in[2];
    const float* Wk  = (const float*)d_in[3];
    const float* bk  = (const float*)d_in[4];
    const float* Wv  = (const float*)d_in[5];
    const float* bv  = (const float*)d_in[6];
    const float* Wo  = (const float*)d_in[7];
    const float* bo  = (const float*)d_in[8];
    const float* Wih = (const float*)d_in[9];
    const float* bih = (const float*)d_in[10];
    const float* Whh = (const float*)d_in[11];
    const float* bhh = (const float*)d_in[12];
    const float* Wfc = (const float*)d_in[13];
    const float* bfc = (const float*)d_in[14];
    float* out = (float*)d_out;
    char* base = (char*)d_ws;

    // [0,16M):  x_f16 -> h0 packed-fp16 slab (16MB)
    // [32,48M): Q_f16 -> ctx f16
    // [48,64M): K_f16 -> atten_out f16 -> h1 packed-fp16 slab
    // [64,80M): Vt f16
    // [80,112M): pre f32 (pre0, then pre1)
    // [112,116M): 8 fp16 weight copies
    _Float16* xh   = (_Float16*)(base);
    unsigned* h0u  = (unsigned*)(base);
    _Float16* h0h  = (_Float16*)(base);
    _Float16* Qh   = (_Float16*)(base + ((size_t)32 << 20));
    _Float16* Kh   = (_Float16*)(base + ((size_t)48 << 20));
    unsigned* h1u  = (unsigned*)(base + ((size_t)48 << 20));
    _Float16* h1h  = (_Float16*)(base + ((size_t)48 << 20));
    _Float16* Vth  = (_Float16*)(base + ((size_t)64 << 20));
    float*    pre  = (float*)(base + ((size_t)80 << 20));
    _Float16* wgt  = (_Float16*)(base + ((size_t)112 << 20));
    const size_t WSZ = 512 * 512;

    cast_h<<<dim3(4096), dim3(256), 0, stream>>>(x, xh, (B * S * E) / 4);
    cast_h<<<dim3(256), dim3(256), 0, stream>>>(Wq, wgt + 0 * WSZ, WSZ / 4);
    cast_h<<<dim3(256), dim3(256), 0, stream>>>(Wk, wgt + 1 * WSZ, WSZ / 4);
    cast_h<<<dim3(256), dim3(256), 0, stream>>>(Wv, wgt + 2 * WSZ, WSZ / 4);
    cast_h<<<dim3(256), dim3(256), 0, stream>>>(Wo, wgt + 3 * WSZ, WSZ / 4);
    cast_h<<<dim3(256), dim3(256), 0, stream>>>(Wih, wgt + 4 * WSZ, WSZ / 4);
    cast_h<<<dim3(256), dim3(256), 0, stream>>>(Wih + WSZ, wgt + 5 * WSZ, WSZ / 4);
    cast_h<<<dim3(256), dim3(256), 0, stream>>>(Whh, wgt + 6 * WSZ, WSZ / 4);
    cast_h<<<dim3(256), dim3(256), 0, stream>>>(Whh + WSZ, wgt + 7 * WSZ, WSZ / 4);

    const dim3 gg(4, 128), blk(256);
    gemm_mfma<1><<<gg, blk, 0, stream>>>(xh, wgt + 0 * WSZ, bq, Qh, B * S, E, E);
    gemm_mfma<1><<<gg, blk, 0, stream>>>(xh, wgt + 1 * WSZ, bk, Kh, B * S, E, E);
    gemm_mfma<2><<<gg, blk, 0, stream>>>(xh, wgt + 2 * WSZ, bv, Vth, B * S, E, E);
    attn_mfma<<<dim3(B * NH * 8), blk, 0, stream>>>(Qh, Kh, Vth);
    gemm_mfma<1><<<gg, blk, 0, stream>>>(Qh, wgt + 3 * WSZ, bo, Kh, B * S, E, E);
    gemm_mfma<3><<<gg, blk, 0, stream>>>(Kh, wgt + 4 * WSZ, bih, pre, B * S, H, E);

    // layer 0 (h0 slab overwrites x_f16, already consumed)
    fill_poison<<<dim3(1024), blk, 0, stream>>>((uint4*)base, (16 << 20) / 16);
    rnn_persist<<<dim3(256), blk, 0, stream>>>(pre, wgt + 6 * WSZ, bhh, h0u);
    // layer-1 input projection: pre1 = h0 @ Wih1^T + bih1 (rows already t*32+b)
    gemm_mfma<0><<<gg, blk, 0, stream>>>(h0h, wgt + 5 * WSZ, bih + 512, pre, B * S, H, H);
    // layer 1 (h1 slab overwrites atten_out, already consumed)
    fill_poison<<<dim3(1024), blk, 0, stream>>>((uint4*)(base + ((size_t)48 << 20)),
                                                (16 << 20) / 16);
    rnn_persist<<<dim3(256), blk, 0, stream>>>(pre, wgt + 7 * WSZ, bhh + 512, h1u);
    fc_out<<<dim3(32), dim3(64), 0, stream>>>(h1h + (size_t)511 * B * H, Wfc, bfc, out);
}

// Round 18
// 1223.463 us; speedup vs baseline: 3.3655x; 1.1361x over previous
//
#include <hip/hip_runtime.h>
#include <hip/hip_fp16.h>

#define B 32
#define S 512
#define E 512
#define H 512
#define NH 8
#define HD 64
#define POISON 0x7FC0DEADu

typedef _Float16 h16x8 __attribute__((ext_vector_type(8)));
typedef _Float16 h16x4 __attribute__((ext_vector_type(4)));
typedef _Float16 h16x2 __attribute__((ext_vector_type(2)));
typedef float f32x4 __attribute__((ext_vector_type(4)));

#if __has_builtin(__builtin_amdgcn_fdot2)
__device__ __forceinline__ float dot2f(h16x2 a, h16x2 b, float c) {
    return __builtin_amdgcn_fdot2(a, b, c, false);
}
#else
__device__ __forceinline__ float dot2f(h16x2 a, h16x2 b, float c) {
    return c + (float)a[0] * (float)b[0] + (float)a[1] * (float)b[1];
}
#endif

__device__ __forceinline__ h16x2 pr(h16x8 v, int q) {
    h16x2 r; r[0] = v[2 * q]; r[1] = v[2 * q + 1]; return r;
}

// ---------------- fp32 -> fp16 cast (vectorized, grid-stride) ----------------
__global__ __launch_bounds__(256) void cast_h(const float* __restrict__ src,
                                              _Float16* __restrict__ dst, int n4) {
    int i = blockIdx.x * 256 + threadIdx.x;
    const int stride = gridDim.x * 256;
    for (; i < n4; i += stride) {
        float4 v = ((const float4*)src)[i];
        h16x4 o;
        o[0] = (_Float16)v.x; o[1] = (_Float16)v.y;
        o[2] = (_Float16)v.z; o[3] = (_Float16)v.w;
        ((h16x4*)dst)[i] = o;
    }
}

// ---------------- MFMA GEMM: C[M,N] = A[M,K] @ W[N,K]^T + bias ----------------
// OMODE 0: f32 row-major. 1: f16 row-major. 2: f16 scattered to Vt[(b*8+h)*64+d][s].
// 3: f32 time-major scatter row r=b*512+s -> C[(s*32+b)*N+c].
template <int OMODE>
__global__ __launch_bounds__(256) void gemm_mfma(const _Float16* __restrict__ A,
                                                 const _Float16* __restrict__ W,
                                                 const float* __restrict__ bias,
                                                 void* __restrict__ Cout,
                                                 int M, int N, int K) {
    __shared__ __align__(16) _Float16 Als[128 * 32];
    __shared__ __align__(16) _Float16 Bls[128 * 32];
    const int tid = threadIdx.x;
    const int m0 = blockIdx.y * 128;
    const int n0 = blockIdx.x * 128;
    const int lane = tid & 63;
    const int w = tid >> 6;
    const int wm = w >> 1, wn = w & 1;
    f32x4 acc[4][4] = {};

    const int srow = tid >> 1;
    const int shalf = tid & 1;
    const _Float16* Ag = A + (size_t)(m0 + srow) * K + shalf * 16;
    const _Float16* Wg = W + (size_t)(n0 + srow) * K + shalf * 16;

    for (int k0 = 0; k0 < K; k0 += 32) {
        h16x8 a0 = *(const h16x8*)(Ag + k0);
        h16x8 a1 = *(const h16x8*)(Ag + k0 + 8);
        h16x8 b0 = *(const h16x8*)(Wg + k0);
        h16x8 b1 = *(const h16x8*)(Wg + k0 + 8);
        __syncthreads();
        *(h16x8*)&Als[srow * 32 + shalf * 16] = a0;
        *(h16x8*)&Als[srow * 32 + shalf * 16 + 8] = a1;
        *(h16x8*)&Bls[srow * 32 + shalf * 16] = b0;
        *(h16x8*)&Bls[srow * 32 + shalf * 16 + 8] = b1;
        __syncthreads();
        h16x8 af[4], bf[4];
#pragma unroll
        for (int mt = 0; mt < 4; ++mt)
            af[mt] = *(const h16x8*)&Als[(wm * 64 + mt * 16 + (lane & 15)) * 32 + (lane >> 4) * 8];
#pragma unroll
        for (int nt = 0; nt < 4; ++nt)
            bf[nt] = *(const h16x8*)&Bls[(wn * 64 + nt * 16 + (lane & 15)) * 32 + (lane >> 4) * 8];
#pragma unroll
        for (int mt = 0; mt < 4; ++mt)
#pragma unroll
            for (int nt = 0; nt < 4; ++nt)
                acc[mt][nt] = __builtin_amdgcn_mfma_f32_16x16x32_f16(af[mt], bf[nt], acc[mt][nt], 0, 0, 0);
    }

    float* Cf = (float*)Cout;
    _Float16* Ch = (_Float16*)Cout;
    const int colb = n0 + wn * 64 + (lane & 15);
    const int rowb = m0 + wm * 64 + ((lane >> 4) << 2);
#pragma unroll
    for (int mt = 0; mt < 4; ++mt) {
#pragma unroll
        for (int nt = 0; nt < 4; ++nt) {
            const int c = colb + nt * 16;
            const float bv = bias[c];
            if (OMODE == 2) {
                const int R0 = rowb + mt * 16;
                const int bb = R0 >> 9, s = R0 & 511, hh = c >> 6, d = c & 63;
                h16x4 pk;
#pragma unroll
                for (int j = 0; j < 4; ++j) pk[j] = (_Float16)(acc[mt][nt][j] + bv);
                *(h16x4*)&Ch[((size_t)(bb * 8 + hh) * 64 + d) * 512 + s] = pk;
            } else {
#pragma unroll
                for (int j = 0; j < 4; ++j) {
                    const int R = rowb + mt * 16 + j;
                    const float v = acc[mt][nt][j] + bv;
                    if (OMODE == 0) Cf[(size_t)R * N + c] = v;
                    else if (OMODE == 3) Cf[((size_t)(R & 511) * 32 + (R >> 9)) * N + c] = v;
                    else Ch[(size_t)R * N + c] = (_Float16)v;
                }
            }
        }
    }
}

// ---------------- MFMA flash attention: per (b, h, 64-row q-tile) ----------------
__global__ __launch_bounds__(256) void attn_mfma(_Float16* __restrict__ Qb,
                                                 const _Float16* __restrict__ Kb,
                                                 const _Float16* __restrict__ Vt) {
    __shared__ __align__(16) _Float16 Qs[64 * 72];
    __shared__ __align__(16) _Float16 Ks[64 * 72];
    __shared__ __align__(16) _Float16 Vs[64 * 72];
    __shared__ __align__(16) _Float16 Ps[4 * 16 * 72];
    const int tid = threadIdx.x;
    const int lane = tid & 63;
    const int w = tid >> 6;
    const int qt = blockIdx.x & 7;
    const int h = (blockIdx.x >> 3) & 7;
    const int b = blockIdx.x >> 6;
    const size_t qrow0 = (size_t)b * 512 + qt * 64;
    const int col0 = h * 64;

    {
        const int r = tid >> 2;
        const int c0 = (tid & 3) << 4;
        const _Float16* gq = &Qb[(qrow0 + r) * 512 + col0 + c0];
        *(h16x8*)&Qs[r * 72 + c0] = *(const h16x8*)(gq);
        *(h16x8*)&Qs[r * 72 + c0 + 8] = *(const h16x8*)(gq + 8);
    }
    __syncthreads();
    h16x8 aq[2];
#pragma unroll
    for (int ks = 0; ks < 2; ++ks)
        aq[ks] = *(const h16x8*)&Qs[(w * 16 + (lane & 15)) * 72 + ks * 32 + (lane >> 4) * 8];

    float m[4] = {-1e30f, -1e30f, -1e30f, -1e30f};
    float l[4] = {0.f, 0.f, 0.f, 0.f};
    f32x4 acco[4] = {};

    for (int kt = 0; kt < 8; ++kt) {
        __syncthreads();
        {
            const int r = tid >> 2;
            const int c0 = (tid & 3) << 4;
            const _Float16* gk = &Kb[((size_t)b * 512 + kt * 64 + r) * 512 + col0 + c0];
            *(h16x8*)&Ks[r * 72 + c0] = *(const h16x8*)(gk);
            *(h16x8*)&Ks[r * 72 + c0 + 8] = *(const h16x8*)(gk + 8);
            const _Float16* gv = &Vt[((size_t)(b * 8 + h) * 64 + r) * 512 + kt * 64 + c0];
            *(h16x8*)&Vs[r * 72 + c0] = *(const h16x8*)(gv);
            *(h16x8*)&Vs[r * 72 + c0 + 8] = *(const h16x8*)(gv + 8);
        }
        __syncthreads();
        f32x4 accs[4] = {};
#pragma unroll
        for (int nt = 0; nt < 4; ++nt) {
#pragma unroll
            for (int ks = 0; ks < 2; ++ks) {
                h16x8 bk = *(const h16x8*)&Ks[(nt * 16 + (lane & 15)) * 72 + ks * 32 + (lane >> 4) * 8];
                accs[nt] = __builtin_amdgcn_mfma_f32_16x16x32_f16(aq[ks], bk, accs[nt], 0, 0, 0);
            }
        }
#pragma unroll
        for (int j = 0; j < 4; ++j) {
            float v = fmaxf(fmaxf(accs[0][j], accs[1][j]), fmaxf(accs[2][j], accs[3][j]));
#pragma unroll
            for (int o = 1; o < 16; o <<= 1) v = fmaxf(v, __shfl_xor(v, o, 64));
            const float mn = fmaxf(m[j], v);
            const float scl = __expf(0.125f * (m[j] - mn));
            m[j] = mn;
            l[j] *= scl;
#pragma unroll
            for (int nt2 = 0; nt2 < 4; ++nt2) acco[nt2][j] *= scl;
            float ps = 0.f;
            const int prow = ((lane >> 4) << 2) + j;
#pragma unroll
            for (int nt = 0; nt < 4; ++nt) {
                const float p = __expf(0.125f * (accs[nt][j] - mn));
                ps += p;
                Ps[w * 16 * 72 + prow * 72 + nt * 16 + (lane & 15)] = (_Float16)p;
            }
#pragma unroll
            for (int o = 1; o < 16; o <<= 1) ps += __shfl_xor(ps, o, 64);
            l[j] += ps;
        }
        __syncthreads();
#pragma unroll
        for (int ks2 = 0; ks2 < 2; ++ks2) {
            h16x8 pa = *(const h16x8*)&Ps[w * 16 * 72 + (lane & 15) * 72 + ks2 * 32 + (lane >> 4) * 8];
#pragma unroll
            for (int nt2 = 0; nt2 < 4; ++nt2) {
                h16x8 bv = *(const h16x8*)&Vs[(nt2 * 16 + (lane & 15)) * 72 + ks2 * 32 + (lane >> 4) * 8];
                acco[nt2] = __builtin_amdgcn_mfma_f32_16x16x32_f16(pa, bv, acco[nt2], 0, 0, 0);
            }
        }
    }
#pragma unroll
    for (int j = 0; j < 4; ++j) {
        const float inv = 1.0f / l[j];
        const size_t r = qrow0 + w * 16 + ((lane >> 4) << 2) + j;
#pragma unroll
        for (int nt2 = 0; nt2 < 4; ++nt2)
            Qb[r * 512 + col0 + nt2 * 16 + (lane & 15)] = (_Float16)(acco[nt2][j] * inv);
    }
}

// ---------------- poison fill ----------------
__global__ __launch_bounds__(256) void fill_poison(uint4* __restrict__ p, int n) {
    const uint4 v = {POISON, POISON, POISON, POISON};
    int i = blockIdx.x * 256 + threadIdx.x;
    const int st = gridDim.x * 256;
    for (; i < n; i += st) p[i] = v;
}

__device__ __forceinline__ unsigned long long poll2(const unsigned* p) {
    unsigned long long v = __hip_atomic_load((const unsigned long long*)p,
                                             __ATOMIC_RELAXED, __HIP_MEMORY_SCOPE_AGENT);
    while ((unsigned)v == POISON || (unsigned)(v >> 32) == POISON) {
        __builtin_amdgcn_s_sleep(1);
        v = __hip_atomic_load((const unsigned long long*)p,
                              __ATOMIC_RELAXED, __HIP_MEMORY_SCOPE_AGENT);
    }
    return v;
}

// ---------------- persistent single-layer RNN (256 blocks = 32 b x 8 slices) --------
// Round-12 structure (verified best): fp16 weights streamed from L2 with loads issued
// before the poll; per-thread u64 poison-poll dataflow; part[][] LDS reduce.
__global__ __launch_bounds__(256) void rnn_persist(const float* __restrict__ pre,
                                                   const _Float16* __restrict__ W16,
                                                   const float* __restrict__ bhh,
                                                   unsigned* __restrict__ hbuf,
                                                   _Float16* __restrict__ hbuf_h) {
    __shared__ float hl[512];
    __shared__ float part[64][17];
    const int tid = threadIdx.x;
    const int b = blockIdx.x & 31;
    const int sl = blockIdx.x >> 5;
    const int jq = tid & 15, kg = tid >> 4;
    const int jbase = sl * 64, k0 = kg * 32;
    const int j64 = tid & 63;

    const _Float16* w0p = W16 + (size_t)(jbase + jq * 4 + 0) * 512 + k0;
    const _Float16* w1p = W16 + (size_t)(jbase + jq * 4 + 1) * 512 + k0;
    const _Float16* w2p = W16 + (size_t)(jbase + jq * 4 + 2) * 512 + k0;
    const _Float16* w3p = W16 + (size_t)(jbase + jq * 4 + 3) * 512 + k0;
    const float bj = bhh[jbase + j64];

    for (int t = 0; t < S; ++t) {
        // issue weight + pre loads first so they fly during the poll spin
        h16x8 w0[4], w1[4], w2[4], w3[4];
#pragma unroll
        for (int c8 = 0; c8 < 4; ++c8) {
            w0[c8] = *(const h16x8*)(w0p + c8 * 8);
            w1[c8] = *(const h16x8*)(w1p + c8 * 8);
            w2[c8] = *(const h16x8*)(w2p + c8 * 8);
            w3[c8] = *(const h16x8*)(w3p + c8 * 8);
        }
        const float pv = pre[((size_t)t * 32 + b) * 512 + jbase + j64];
        float a0 = 0.f, a1 = 0.f, a2 = 0.f, a3 = 0.f;
        if (t > 0) {
            const unsigned long long v = poll2(hbuf + (size_t)(t - 1) * (B * H) + b * H + tid * 2);
            hl[tid * 2] = __uint_as_float((unsigned)v);
            hl[tid * 2 + 1] = __uint_as_float((unsigned)(v >> 32));
            __syncthreads();
            f32x4 hw[8];
#pragma unroll
            for (int c = 0; c < 8; ++c) hw[c] = *(const f32x4*)&hl[k0 + c * 4];
            h16x2 hp[16];
#pragma unroll
            for (int c = 0; c < 8; ++c) {
                h16x2 p0, p1;
                p0[0] = (_Float16)hw[c][0]; p0[1] = (_Float16)hw[c][1];
                p1[0] = (_Float16)hw[c][2]; p1[1] = (_Float16)hw[c][3];
                hp[2 * c] = p0; hp[2 * c + 1] = p1;
            }
#pragma unroll
            for (int c8 = 0; c8 < 4; ++c8) {
#pragma unroll
                for (int q = 0; q < 4; ++q) {
                    a0 = dot2f(pr(w0[c8], q), hp[c8 * 4 + q], a0);
                    a1 = dot2f(pr(w1[c8], q), hp[c8 * 4 + q], a1);
                    a2 = dot2f(pr(w2[c8], q), hp[c8 * 4 + q], a2);
                    a3 = dot2f(pr(w3[c8], q), hp[c8 * 4 + q], a3);
                }
            }
        }
        part[jq * 4 + 0][kg] = a0;
        part[jq * 4 + 1][kg] = a1;
        part[jq * 4 + 2][kg] = a2;
        part[jq * 4 + 3][kg] = a3;
        __syncthreads();   // also: hl fully consumed
        if (tid < 64) {
            float s2 = 0.f;
#pragma unroll
            for (int i = 0; i < 16; ++i) s2 += part[tid][i];
            s2 += bj + pv;
            s2 = fminf(fmaxf(s2, -15.f), 15.f);
            const float ex = __expf(2.f * s2);
            const float hval = (ex - 1.f) / (ex + 1.f);
            const size_t idx = (size_t)t * (B * H) + b * H + jbase + tid;
            __hip_atomic_store(&hbuf[idx], __float_as_uint(hval),
                               __ATOMIC_RELAXED, __HIP_MEMORY_SCOPE_AGENT);
            hbuf_h[idx] = (_Float16)hval;
        }
        __syncthreads();   // part[] + hl protected before next iteration
    }
}

// ---------------- final FC: out[b] = h1[511][b,:] . Wfc[0,:] + bfc[0] ----------------
__global__ __launch_bounds__(64) void fc_out(const unsigned* __restrict__ hbits,
                                             const float* __restrict__ Wfc,
                                             const float* __restrict__ bfc,
                                             float* __restrict__ out) {
    int b = blockIdx.x;
    int t = threadIdx.x;
    float a = 0.f;
    for (int j = t; j < 512; j += 64) a += __uint_as_float(hbits[b * 512 + j]) * Wfc[j];
#pragma unroll
    for (int o = 32; o; o >>= 1) a += __shfl_down(a, o, 64);
    if (t == 0) out[b] = a + bfc[0];
}

extern "C" void kernel_launch(void* const* d_in, const int* in_sizes, int n_in,
                              void* d_out, int out_size, void* d_ws, size_t ws_size,
                              hipStream_t stream) {
    const float* x   = (const float*)d_in[0];
    const float* Wq  = (const float*)d_in[1];
    const float* bq  = (const float*)d_in[2];
    const float* Wk  = (const float*)d_in[3];
    const float* bk  = (const float*)d_in[4];
    const float* Wv  = (const float*)d_in[5];
    const float* bv  = (const float*)d_in[6];
    const float* Wo  = (const float*)d_in[7];
    const float* bo  = (const float*)d_in[8];
    const float* Wih = (const float*)d_in[9];
    const float* bih = (const float*)d_in[10];
    const float* Whh = (const float*)d_in[11];
    const float* bhh = (const float*)d_in[12];
    const float* Wfc = (const float*)d_in[13];
    const float* bfc = (const float*)d_in[14];
    float* out = (float*)d_out;
    char* base = (char*)d_ws;

    _Float16* xh   = (_Float16*)(base);
    unsigned* h0u  = (unsigned*)(base);
    _Float16* Qh   = (_Float16*)(base + ((size_t)32 << 20));
    _Float16* h0h  = (_Float16*)(base + ((size_t)32 << 20));
    _Float16* Kh   = (_Float16*)(base + ((size_t)48 << 20));
    unsigned* h1u  = (unsigned*)(base + ((size_t)48 << 20));
    _Float16* Vth  = (_Float16*)(base + ((size_t)64 << 20));
    float*    pre  = (float*)(base + ((size_t)80 << 20));
    _Float16* wgt  = (_Float16*)(base + ((size_t)112 << 20));
    const size_t WSZ = 512 * 512;

    cast_h<<<dim3(4096), dim3(256), 0, stream>>>(x, xh, (B * S * E) / 4);
    cast_h<<<dim3(256), dim3(256), 0, stream>>>(Wq, wgt + 0 * WSZ, WSZ / 4);
    cast_h<<<dim3(256), dim3(256), 0, stream>>>(Wk, wgt + 1 * WSZ, WSZ / 4);
    cast_h<<<dim3(256), dim3(256), 0, stream>>>(Wv, wgt + 2 * WSZ, WSZ / 4);
    cast_h<<<dim3(256), dim3(256), 0, stream>>>(Wo, wgt + 3 * WSZ, WSZ / 4);
    cast_h<<<dim3(256), dim3(256), 0, stream>>>(Wih, wgt + 4 * WSZ, WSZ / 4);
    cast_h<<<dim3(256), dim3(256), 0, stream>>>(Wih + WSZ, wgt + 5 * WSZ, WSZ / 4);
    cast_h<<<dim3(256), dim3(256), 0, stream>>>(Whh, wgt + 6 * WSZ, WSZ / 4);
    cast_h<<<dim3(256), dim3(256), 0, stream>>>(Whh + WSZ, wgt + 7 * WSZ, WSZ / 4);

    const dim3 gg(4, 128), blk(256);
    gemm_mfma<1><<<gg, blk, 0, stream>>>(xh, wgt + 0 * WSZ, bq, Qh, B * S, E, E);
    gemm_mfma<1><<<gg, blk, 0, stream>>>(xh, wgt + 1 * WSZ, bk, Kh, B * S, E, E);
    gemm_mfma<2><<<gg, blk, 0, stream>>>(xh, wgt + 2 * WSZ, bv, Vth, B * S, E, E);
    attn_mfma<<<dim3(B * NH * 8), blk, 0, stream>>>(Qh, Kh, Vth);
    gemm_mfma<1><<<gg, blk, 0, stream>>>(Qh, wgt + 3 * WSZ, bo, Kh, B * S, E, E);
    gemm_mfma<3><<<gg, blk, 0, stream>>>(Kh, wgt + 4 * WSZ, bih, pre, B * S, H, E);

    fill_poison<<<dim3(1024), blk, 0, stream>>>((uint4*)base, (32 << 20) / 16);
    rnn_persist<<<dim3(256), blk, 0, stream>>>(pre, wgt + 6 * WSZ, bhh, h0u, h0h);
    gemm_mfma<0><<<gg, blk, 0, stream>>>(h0h, wgt + 5 * WSZ, bih + 512, pre, B * S, H, H);
    fill_poison<<<dim3(1024), blk, 0, stream>>>((uint4*)(base + ((size_t)48 << 20)),
                                                (32 << 20) / 16);
    rnn_persist<<<dim3(256), blk, 0, stream>>>(pre, wgt + 7 * WSZ, bhh + 512, h1u, h0h);
    fc_out<<<dim3(32), dim3(64), 0, stream>>>(h1u + (size_t)511 * B * H, Wfc, bfc, out);
}